// Round 1
// baseline (399.684 us; speedup 1.0000x reference)
//
#include <hip/hip_runtime.h>
#include <math.h>

// Problem constants
// B=8, H=8, N=4096, D=64, RPE_DIM=64, LAYERS=3
// fft_size = 8192, nf = 4097
// Complex FFT length M2 = 4096 (even/odd packed real FFT of 8192)

#define PADF(i) ((i) + ((i) >> 5))   // LDS pad: +1 float per 32

__device__ __forceinline__ unsigned dr4_12(unsigned k) {
    // digit-reverse base-4 of a 12-bit index (6 digits)
    unsigned rb = __brev(k) >> 20;                       // 12-bit bit reversal
    return ((rb & 0x555u) << 1) | ((rb >> 1) & 0x555u);  // swap adjacent bit pairs
}

// ---------------------------------------------------------------------------
// Kernel 1: RPE MLP. One wave (64 threads) per frequency row k = 0..4096.
// res[k][j], j = h*128 + ri*64 + d  (ri=0 real, ri=1 imag), row-major 1024.
// ---------------------------------------------------------------------------
__global__ __launch_bounds__(64) void rpe_mlp_kernel(
    const float* __restrict__ w_in, const float* __restrict__ b_in,
    const float* __restrict__ w_layers, const float* __restrict__ b_layers,
    const float* __restrict__ w_out, const float* __restrict__ b_out,
    float* __restrict__ res)
{
    const int k = blockIdx.x;      // 0..4096
    const int lane = threadIdx.x;  // 0..63
    const float pos = 3.14159265358979323846f * (float)k * (1.0f / 4096.0f);

    float xv = fmaf(pos, w_in[lane], b_in[lane]);

    for (int l = 0; l < 3; ++l) {
        float ss = xv * xv;
        #pragma unroll
        for (int o = 1; o < 64; o <<= 1) ss += __shfl_xor(ss, o, 64);
        float rms = sqrtf(ss * (1.0f / 64.0f));
        float r = xv / (rms + 1e-8f);
        r = r > 0.0f ? r : 0.0f;
        const float* W = w_layers + l * 64 * 64;
        float acc = b_layers[l * 64 + lane];
        for (int i = 0; i < 64; ++i) {
            float rv = __shfl(r, i, 64);
            acc = fmaf(rv, W[i * 64 + lane], acc);
        }
        xv = acc;
    }

    float ss = xv * xv;
    #pragma unroll
    for (int o = 1; o < 64; o <<= 1) ss += __shfl_xor(ss, o, 64);
    float rms = sqrtf(ss * (1.0f / 64.0f));
    float r = xv / (rms + 1e-8f);
    r = r > 0.0f ? r : 0.0f;

    float acc[16];
    #pragma unroll
    for (int u = 0; u < 16; ++u) acc[u] = b_out[u * 64 + lane];
    for (int i = 0; i < 64; ++i) {
        float rv = __shfl(r, i, 64);
        const float* Wrow = w_out + i * 1024;
        #pragma unroll
        for (int u = 0; u < 16; ++u)
            acc[u] = fmaf(rv, Wrow[u * 64 + lane], acc[u]);
    }
    float* dst = res + (size_t)k * 1024;
    #pragma unroll
    for (int u = 0; u < 16; ++u) dst[u * 64 + lane] = acc[u];
}

// ---------------------------------------------------------------------------
// Kernel 2: fused rfft(8192) -> filter multiply -> irfft(8192), one workgroup
// per (b,h,d) column. Complex FFT length 4096 in LDS, radix-4 DIF forward
// (natural -> digit-reversed) and radix-4 DIT inverse (digit-reversed ->
// natural). XCD-aware blockIdx swizzle: all 64 d of one (b,h) slab share XCD.
// ---------------------------------------------------------------------------
__global__ __launch_bounds__(256) void fftconv_kernel(
    const float* __restrict__ x, const float* __restrict__ res,
    float* __restrict__ out)
{
    __shared__ float re[PADF(4095) + 1];
    __shared__ float im[PADF(4095) + 1];

    const int tid = threadIdx.x;
    const int blk = blockIdx.x;                       // 0..4095
    const int d = (blk >> 3) & 63;
    const int slab = (blk & 7) | ((blk >> 9) << 3);   // b*8 + h, XCD = slab%8
    const int h = slab & 7;
    const size_t base = (size_t)slab * 4096 * 64 + (size_t)d;
    const float* xc = x + base;
    float* oc = out + base;
    const int c = h * 128 + d;                        // filter column (real); +64 imag

    // ---- load & pack: z[m] = x[2m] + i*x[2m+1] (m<2048), zero pad above ----
    for (int m = tid; m < 2048; m += 256) {
        re[PADF(m)] = xc[(size_t)(2 * m) * 64];
        im[PADF(m)] = xc[(size_t)(2 * m + 1) * 64];
    }
    for (int m = 2048 + tid; m < 4096; m += 256) {
        re[PADF(m)] = 0.0f;
        im[PADF(m)] = 0.0f;
    }
    __syncthreads();

    // ---- forward radix-4 DIF, W = exp(-2*pi*i/(4S)) ----
    for (int S = 1024; S >= 1; S >>= 2) {
        const float ab = -6.283185307179586f / (float)(4 * S);
        for (int j = tid; j < 1024; j += 256) {
            const int q = j & (S - 1);
            const int i0 = ((j & ~(S - 1)) << 2) | q;
            const int p0 = PADF(i0), p1 = PADF(i0 + S), p2 = PADF(i0 + 2 * S), p3 = PADF(i0 + 3 * S);
            float x0r = re[p0], x0i = im[p0], x1r = re[p1], x1i = im[p1];
            float x2r = re[p2], x2i = im[p2], x3r = re[p3], x3i = im[p3];
            float A0r = x0r + x2r, A0i = x0i + x2i;
            float A1r = x0r - x2r, A1i = x0i - x2i;
            float A2r = x1r + x3r, A2i = x1i + x3i;
            float A3r = x1r - x3r, A3i = x1i - x3i;
            float s1, c1;
            __sincosf(ab * (float)q, &s1, &c1);
            float c2 = c1 * c1 - s1 * s1, s2 = 2.0f * c1 * s1;
            float c3 = c2 * c1 - s2 * s1, s3 = s2 * c1 + c2 * s1;
            re[p0] = A0r + A2r; im[p0] = A0i + A2i;
            float t1r = A1r + A3i, t1i = A1i - A3r;          // A1 - i*A3
            re[p1] = t1r * c1 - t1i * s1; im[p1] = t1r * s1 + t1i * c1;
            float t2r = A0r - A2r, t2i = A0i - A2i;
            re[p2] = t2r * c2 - t2i * s2; im[p2] = t2r * s2 + t2i * c2;
            float t3r = A1r - A3i, t3i = A1i + A3r;          // A1 + i*A3
            re[p3] = t3r * c3 - t3i * s3; im[p3] = t3r * s3 + t3i * c3;
        }
        __syncthreads();
    }

    // ---- spectral: unpack rfft, multiply by filter, repack for irfft ----
    // Slot dr4(k) holds C[k]. For k in [1,2047]: pair (k, 4096-k).
    for (int k = tid; k <= 2048; k += 256) {
        if (k == 0) {
            float C0r = re[0], C0i = im[0];
            float X0 = C0r + C0i;        // X[0]    (real)
            float XN = C0r - C0i;        // X[4096] (real)
            float a0 = res[c];                            // imag forced 0
            float aN = res[(size_t)4096 * 1024 + c];      // imag forced 0
            float S0 = a0 * X0, SN = aN * XN;
            re[0] = 0.5f * (S0 + SN);
            im[0] = 0.5f * (S0 - SN);
        } else if (k == 2048) {
            const int p = PADF(2);       // dr4(2048) = 2
            float Cr = re[p], Ci = im[p];
            float ar = res[(size_t)2048 * 1024 + c];
            float ai = res[(size_t)2048 * 1024 + c + 64];
            // X[2048] = conj(C); S = a * X ; z'[2048] = conj(S)
            float Sr = ar * Cr + ai * Ci;
            float Si = ai * Cr - ar * Ci;
            re[p] = Sr; im[p] = -Si;
        } else {
            const int pk = PADF((int)dr4_12((unsigned)k));
            const int pm = PADF((int)dr4_12((unsigned)(4096 - k)));
            float Ckr = re[pk], Cki = im[pk];
            float Cmr = re[pm], Cmi = im[pm];
            float Er = 0.5f * (Ckr + Cmr), Ei = 0.5f * (Cki - Cmi);   // E=(Ck+conj(Cm))/2
            float Dr = 0.5f * (Ckr - Cmr), Di = 0.5f * (Cki + Cmi);   // (Ck-conj(Cm))/2
            float Or = Di, Oi = -Dr;                                  // O = -i*(...)
            float sw, cw;
            __sincosf(-6.283185307179586f * (float)k * (1.0f / 8192.0f), &sw, &cw);
            float Tr = Or * cw - Oi * sw, Ti = Or * sw + Oi * cw;     // T = W^k * O
            float Xkr = Er + Tr, Xki = Ei + Ti;                       // X[k]
            float Xmr = Er - Tr, Xmi = Ti - Ei;                       // X[4096-k]=conj(E-T)
            float akr = res[(size_t)k * 1024 + c];
            float aki = res[(size_t)k * 1024 + c + 64];
            float amr = res[(size_t)(4096 - k) * 1024 + c];
            float ami = res[(size_t)(4096 - k) * 1024 + c + 64];
            float Skr = akr * Xkr - aki * Xki, Ski = akr * Xki + aki * Xkr;
            float Smr = amr * Xmr - ami * Xmi, Smi = amr * Xmi + ami * Xmr;
            float Epr = 0.5f * (Skr + Smr), Epi = 0.5f * (Ski - Smi); // (Sk+conj(Sm))/2
            float Ddr = 0.5f * (Skr - Smr), Ddi = 0.5f * (Ski + Smi); // (Sk-conj(Sm))/2
            float Opr = Ddr * cw + Ddi * sw;                          // O' = conj(W^k)*Dd
            float Opi = Ddi * cw - Ddr * sw;
            re[pk] = Epr - Opi; im[pk] = Epi + Opr;                   // z'[k]      = E'+iO'
            re[pm] = Epr + Opi; im[pm] = Opr - Epi;                   // z'[4096-k] = conj(E')+i*conj(O')
        }
    }
    __syncthreads();

    // ---- inverse radix-4 DIT, W = exp(+2*pi*i/(4S)), scale 1/4096 at end ----
    for (int S = 1; S <= 1024; S <<= 2) {
        const float ab = 6.283185307179586f / (float)(4 * S);
        for (int j = tid; j < 1024; j += 256) {
            const int q = j & (S - 1);
            const int i0 = ((j & ~(S - 1)) << 2) | q;
            const int p0 = PADF(i0), p1 = PADF(i0 + S), p2 = PADF(i0 + 2 * S), p3 = PADF(i0 + 3 * S);
            float y0r = re[p0], y0i = im[p0], y1r = re[p1], y1i = im[p1];
            float y2r = re[p2], y2i = im[p2], y3r = re[p3], y3i = im[p3];
            float s1, c1;
            __sincosf(ab * (float)q, &s1, &c1);
            float c2 = c1 * c1 - s1 * s1, s2 = 2.0f * c1 * s1;
            float c3 = c2 * c1 - s2 * s1, s3 = s2 * c1 + c2 * s1;
            float x1r = y1r * c1 - y1i * s1, x1i = y1r * s1 + y1i * c1;
            float x2r = y2r * c2 - y2i * s2, x2i = y2r * s2 + y2i * c2;
            float x3r = y3r * c3 - y3i * s3, x3i = y3r * s3 + y3i * c3;
            float B0r = y0r + x2r, B0i = y0i + x2i;
            float B1r = y0r - x2r, B1i = y0i - x2i;
            float B2r = x1r + x3r, B2i = x1i + x3i;
            float B3r = x1r - x3r, B3i = x1i - x3i;
            re[p0] = B0r + B2r; im[p0] = B0i + B2i;
            re[p1] = B1r - B3i; im[p1] = B1i + B3r;   // B1 + i*B3
            re[p2] = B0r - B2r; im[p2] = B0i - B2i;
            re[p3] = B1r + B3i; im[p3] = B1i - B3r;   // B1 - i*B3
        }
        __syncthreads();
    }

    // ---- store: out[2m] = Re z'[m], out[2m+1] = Im z'[m], first 4096 only ----
    const float sc = 1.0f / 4096.0f;
    for (int m = tid; m < 2048; m += 256) {
        oc[(size_t)(2 * m) * 64]     = re[PADF(m)] * sc;
        oc[(size_t)(2 * m + 1) * 64] = im[PADF(m)] * sc;
    }
}

// ---------------------------------------------------------------------------
extern "C" void kernel_launch(void* const* d_in, const int* in_sizes, int n_in,
                              void* d_out, int out_size, void* d_ws, size_t ws_size,
                              hipStream_t stream) {
    const float* x        = (const float*)d_in[0];
    const float* w_in     = (const float*)d_in[1];
    const float* b_in     = (const float*)d_in[2];
    const float* w_layers = (const float*)d_in[3];
    const float* b_layers = (const float*)d_in[4];
    const float* w_out    = (const float*)d_in[5];
    const float* b_out    = (const float*)d_in[6];
    float* out = (float*)d_out;
    float* res = (float*)d_ws;   // 4097 * 1024 floats = 16.8 MB

    rpe_mlp_kernel<<<4097, 64, 0, stream>>>(w_in, b_in, w_layers, b_layers,
                                            w_out, b_out, res);
    fftconv_kernel<<<4096, 256, 0, stream>>>(x, res, out);
}

// Round 3
// 397.025 us; speedup vs baseline: 1.0067x; 1.0067x over previous
//
#include <hip/hip_runtime.h>
#include <math.h>

// B=8, H=8, N=4096, D=64 ; fft_size=8192, nf=4097 ; packed complex FFT M=4096
// Four-step: 4096 = 64 x 64.  m = 64*m1 + m0,  k = 64*k0 + k1.
// X[64k0+k1] = sum_m0 W64^{m0k0} [ W4096^{m0k1} * sum_m1 W64^{m1k1} z[64m1+m0] ]

#define PI_F 3.14159265358979323846f
#define TWO_PI_F 6.283185307179586f

__device__ __forceinline__ int dr4_3(int k) {   // 3-digit base-4 reverse
    return ((k & 3) << 4) | (k & 12) | ((k >> 4) & 3);
}

// 64-pt radix-4 DIF over row index (natural in -> digit-reversed out).
// sgn=-1 forward (e^{-i}), sgn=+1 inverse. col < ncol selects batch column.
__device__ __forceinline__ void fft64_dif(float* re, float* im, int col, int ncol,
                                          int w, int nw, float sgn, bool act) {
    for (int S = 16; S >= 1; S >>= 2) {
        const float ab = sgn * TWO_PI_F / (float)(4 * S);
        if (act) {
            for (int j = w; j < 16; j += nw) {
                const int q = j & (S - 1);
                const int i0 = ((j & ~(S - 1)) << 2) | q;
                const int p0 = i0 * ncol + col, p1 = (i0 + S) * ncol + col;
                const int p2 = (i0 + 2 * S) * ncol + col, p3 = (i0 + 3 * S) * ncol + col;
                float x0r = re[p0], x0i = im[p0], x1r = re[p1], x1i = im[p1];
                float x2r = re[p2], x2i = im[p2], x3r = re[p3], x3i = im[p3];
                float A0r = x0r + x2r, A0i = x0i + x2i, A1r = x0r - x2r, A1i = x0i - x2i;
                float A2r = x1r + x3r, A2i = x1i + x3i, A3r = x1r - x3r, A3i = x1i - x3i;
                float s1, c1; __sincosf(ab * (float)q, &s1, &c1);
                float c2 = c1 * c1 - s1 * s1, s2 = 2.0f * c1 * s1;
                float c3 = c2 * c1 - s2 * s1, s3 = s2 * c1 + c2 * s1;
                re[p0] = A0r + A2r; im[p0] = A0i + A2i;
                float t1r = A1r - sgn * A3i, t1i = A1i + sgn * A3r;   // A1 + sgn*i*A3
                re[p1] = t1r * c1 - t1i * s1; im[p1] = t1r * s1 + t1i * c1;
                float t2r = A0r - A2r, t2i = A0i - A2i;
                re[p2] = t2r * c2 - t2i * s2; im[p2] = t2r * s2 + t2i * c2;
                float t3r = A1r + sgn * A3i, t3i = A1i - sgn * A3r;   // A1 - sgn*i*A3
                re[p3] = t3r * c3 - t3i * s3; im[p3] = t3r * s3 + t3i * c3;
            }
        }
        __syncthreads();
    }
}

// 64-pt radix-4 DIT (digit-reversed in -> natural out), sgn as above.
__device__ __forceinline__ void fft64_dit(float* re, float* im, int col, int ncol,
                                          int w, int nw, float sgn, bool act) {
    for (int S = 1; S <= 16; S <<= 2) {
        const float ab = sgn * TWO_PI_F / (float)(4 * S);
        if (act) {
            for (int j = w; j < 16; j += nw) {
                const int q = j & (S - 1);
                const int i0 = ((j & ~(S - 1)) << 2) | q;
                const int p0 = i0 * ncol + col, p1 = (i0 + S) * ncol + col;
                const int p2 = (i0 + 2 * S) * ncol + col, p3 = (i0 + 3 * S) * ncol + col;
                float y0r = re[p0], y0i = im[p0], y1r = re[p1], y1i = im[p1];
                float y2r = re[p2], y2i = im[p2], y3r = re[p3], y3i = im[p3];
                float s1, c1; __sincosf(ab * (float)q, &s1, &c1);
                float c2 = c1 * c1 - s1 * s1, s2 = 2.0f * c1 * s1;
                float c3 = c2 * c1 - s2 * s1, s3 = s2 * c1 + c2 * s1;
                float x1r = y1r * c1 - y1i * s1, x1i = y1r * s1 + y1i * c1;
                float x2r = y2r * c2 - y2i * s2, x2i = y2r * s2 + y2i * c2;
                float x3r = y3r * c3 - y3i * s3, x3i = y3r * s3 + y3i * c3;
                float B0r = y0r + x2r, B0i = y0i + x2i, B1r = y0r - x2r, B1i = y0i - x2i;
                float B2r = x1r + x3r, B2i = x1i + x3i, B3r = x1r - x3r, B3i = x1i - x3i;
                re[p0] = B0r + B2r; im[p0] = B0i + B2i;
                re[p1] = B1r - sgn * B3i; im[p1] = B1i + sgn * B3r;   // B1 + sgn*i*B3
                re[p2] = B0r - B2r; im[p2] = B0i - B2i;
                re[p3] = B1r + sgn * B3i; im[p3] = B1i - sgn * B3r;   // B1 - sgn*i*B3
            }
        }
        __syncthreads();
    }
}

// ---------------------------------------------------------------------------
// MLP stage 1: hidden activations r[k][64] (post relu(srms) of layer 3).
// One wave per k row, 4 rows per block.
// ---------------------------------------------------------------------------
__global__ __launch_bounds__(256) void mlp_hidden_kernel(
    const float* __restrict__ w_in, const float* __restrict__ b_in,
    const float* __restrict__ w_layers, const float* __restrict__ b_layers,
    float* __restrict__ rbuf)
{
    const int lane = threadIdx.x & 63;
    const int k = blockIdx.x * 4 + (threadIdx.x >> 6);
    if (k > 4096) return;
    const float pos = PI_F * (float)k * (1.0f / 4096.0f);
    float xv = fmaf(pos, w_in[lane], b_in[lane]);
    for (int l = 0; l < 3; ++l) {
        float ss = xv * xv;
        #pragma unroll
        for (int o = 1; o < 64; o <<= 1) ss += __shfl_xor(ss, o, 64);
        float r = xv / (sqrtf(ss * (1.0f / 64.0f)) + 1e-8f);
        r = fmaxf(r, 0.0f);
        const float* W = w_layers + l * 4096;
        float a0 = 0.f, a1 = 0.f, a2 = 0.f, a3 = 0.f;
        for (int i = 0; i < 64; i += 4) {
            a0 = fmaf(__shfl(r, i, 64),     W[(i) * 64 + lane],     a0);
            a1 = fmaf(__shfl(r, i + 1, 64), W[(i + 1) * 64 + lane], a1);
            a2 = fmaf(__shfl(r, i + 2, 64), W[(i + 2) * 64 + lane], a2);
            a3 = fmaf(__shfl(r, i + 3, 64), W[(i + 3) * 64 + lane], a3);
        }
        xv = ((a0 + a1) + (a2 + a3)) + b_layers[l * 64 + lane];
    }
    float ss = xv * xv;
    #pragma unroll
    for (int o = 1; o < 64; o <<= 1) ss += __shfl_xor(ss, o, 64);
    float r = xv / (sqrtf(ss * (1.0f / 64.0f)) + 1e-8f);
    r = fmaxf(r, 0.0f);
    rbuf[(size_t)k * 64 + lane] = r;
}

// ---------------------------------------------------------------------------
// MLP stage 2: res[4097][1024] = r @ w_out + b_out.  Tile 16k x 256n per wg.
// ---------------------------------------------------------------------------
__global__ __launch_bounds__(256) void mlp_out_kernel(
    const float* __restrict__ rbuf, const float* __restrict__ w_out,
    const float* __restrict__ b_out, float* __restrict__ res)
{
    __shared__ float rl[16 * 64];
    const int tid = threadIdx.x;
    const int nt = blockIdx.x, kt = blockIdx.y;   // nt 0..3, kt 0..256
    for (int it = 0; it < 4; ++it) {
        int idx = it * 256 + tid;          // row*64 + i
        int row = idx >> 6, i = idx & 63;
        int k = kt * 16 + row;
        rl[idx] = (k <= 4096) ? rbuf[(size_t)k * 64 + i] : 0.0f;
    }
    __syncthreads();
    const int n = nt * 256 + tid;
    float acc[16];
    #pragma unroll
    for (int j = 0; j < 16; ++j) acc[j] = 0.0f;
    for (int i = 0; i < 64; ++i) {
        float wv = w_out[(size_t)i * 1024 + n];
        #pragma unroll
        for (int j = 0; j < 16; ++j)
            acc[j] = fmaf(rl[j * 64 + i], wv, acc[j]);
    }
    float bv = b_out[n];
    for (int j = 0; j < 16; ++j) {
        int k = kt * 16 + j;
        if (k <= 4096) res[(size_t)k * 1024 + n] = acc[j] + bv;
    }
}

// ---------------------------------------------------------------------------
// Stage A: per (slab, m0): FFT64 over m1 of z[64m1+m0][d] (m1>=32 is zero),
// times W4096^{-m0*k1}; write Y[slab][k1][m0][d] (float2).
// ---------------------------------------------------------------------------
__global__ __launch_bounds__(256) void fwd1_kernel(const float* __restrict__ x,
                                                   float2* __restrict__ Y)
{
    __shared__ float re[4096], im[4096];   // [m1 64][d 64]
    const int tid = threadIdx.x;
    const int m0 = blockIdx.x, slab = blockIdx.y;
    const float* xs = x + (size_t)slab * 262144;
    for (int it = 0; it < 16; ++it) {                  // 32 m1 x {re,im} x 64 d
        int flat = it * 256 + tid;
        int m1 = flat >> 7, rr = (flat >> 6) & 1, d = flat & 63;
        float v = xs[(size_t)(128 * m1 + 2 * m0 + rr) * 64 + d];
        if (rr == 0) re[m1 * 64 + d] = v; else im[m1 * 64 + d] = v;
    }
    for (int i = 2048 + tid; i < 4096; i += 256) { re[i] = 0.0f; im[i] = 0.0f; }
    __syncthreads();
    const int d = tid & 63, w = tid >> 6;
    fft64_dif(re, im, d, 64, w, 4, -1.0f, true);
    float2* Ys = Y + (size_t)slab * 262144 + (size_t)m0 * 64;
    for (int og = 0; og < 16; ++og) {
        int k1 = og * 4 + w;
        int slot = dr4_3(k1);
        float vr = re[slot * 64 + d], vi = im[slot * 64 + d];
        float ang = -(TWO_PI_F / 4096.0f) * (float)(m0 * k1);
        float s, c; __sincosf(ang, &s, &c);
        Ys[(size_t)k1 * 4096 + d] = make_float2(vr * c - vi * s, vr * s + vi * c);
    }
}

// ---------------------------------------------------------------------------
// Stage B: per (slab, k1-pair): FFT64 over m0 -> C[64k0+k1] ; spectral
// unpack * filter * repack on pairs (k, 4096-k) ; inverse FFT64 over k0 ;
// times W4096^{+m0*k1}; write U[slab][m0][k1][d] (float2).
// ---------------------------------------------------------------------------
__global__ __launch_bounds__(512) void midspec_kernel(const float2* __restrict__ Y,
                                                      const float* __restrict__ res,
                                                      float2* __restrict__ U)
{
    __shared__ float re[8192], im[8192];   // [row 64][col 128]: colA=[0,64) colB=[64,128)
    const int tid = threadIdx.x;
    const int k1p = blockIdx.x;            // 0..32
    const int slab = blockIdx.y;
    const int h = slab & 7;
    const bool pairwg = (k1p >= 1 && k1p <= 31);
    const int k1a = k1p;
    const int k1b = pairwg ? (64 - k1p) : k1p;
    const int NC = pairwg ? 128 : 64;

    const float2* Pa = Y + (size_t)slab * 262144 + (size_t)k1a * 4096;
    for (int it = 0; it < 4; ++it) {
        int idx4 = it * 512 + tid;
        const float4 v = ((const float4*)Pa)[idx4];
        int lin = idx4 * 2, m0 = lin >> 6, d = lin & 63;
        re[m0 * 128 + d] = v.x;     im[m0 * 128 + d] = v.y;
        re[m0 * 128 + d + 1] = v.z; im[m0 * 128 + d + 1] = v.w;
    }
    if (pairwg) {
        const float2* Pb = Y + (size_t)slab * 262144 + (size_t)k1b * 4096;
        for (int it = 0; it < 4; ++it) {
            int idx4 = it * 512 + tid;
            const float4 v = ((const float4*)Pb)[idx4];
            int lin = idx4 * 2, m0 = lin >> 6, d = lin & 63;
            re[m0 * 128 + 64 + d] = v.x;     im[m0 * 128 + 64 + d] = v.y;
            re[m0 * 128 + 64 + d + 1] = v.z; im[m0 * 128 + 64 + d + 1] = v.w;
        }
    }
    __syncthreads();
    const int col = tid & 127, w8 = tid >> 7;
    fft64_dif(re, im, col, 128, w8, 4, -1.0f, col < NC);

    // spectral multiply on conjugate-pairs; each slot touched exactly once
    const int nit = pairwg ? 8 : 4;
    for (int it = 0; it < nit; ++it) {
        int item = it * 512 + tid;         // k0*64 + d
        int k0 = item >> 6, d = item & 63;
        int c = h * 128 + d;
        if (k1p == 0 && k0 == 0) {
            // DC (k=0) and Nyquist-of-packed (k=2048), both per d
            float C0r = re[d], C0i = im[d];                 // slot dr(0)=0
            float X0 = C0r + C0i, XN = C0r - C0i;
            float a0 = res[c], aN = res[(size_t)4096 * 1024 + c];
            float S0 = a0 * X0, SN = aN * XN;
            re[d] = 0.5f * (S0 + SN); im[d] = 0.5f * (S0 - SN);
            int p2 = 2 * 128 + d;                           // slot dr(32)=2
            float Cr = re[p2], Ci = im[p2];
            float ar = res[(size_t)2048 * 1024 + c], ai = res[(size_t)2048 * 1024 + c + 64];
            float Sr = ar * Cr + ai * Ci, Si = ai * Cr - ar * Ci;
            re[p2] = Sr; im[p2] = -Si;
        } else {
            int k0p, coff;
            if (pairwg)          { k0p = 63 - k0;        coff = 64; }
            else if (k1p == 0)   { k0p = (64 - k0) & 63; coff = 0;  }
            else /* k1p == 32 */ { k0p = 63 - k0;        coff = 0;  }
            int sa = dr4_3(k0)  * 128 + d;
            int sb = dr4_3(k0p) * 128 + coff + d;
            int k  = k0 * 64 + k1a;
            int km = 4096 - k;
            float Ckr = re[sa], Cki = im[sa];
            float Cmr = re[sb], Cmi = im[sb];
            float Er = 0.5f * (Ckr + Cmr), Ei = 0.5f * (Cki - Cmi);
            float Dr = 0.5f * (Ckr - Cmr), Di = 0.5f * (Cki + Cmi);
            float Or = Di, Oi = -Dr;
            float sw, cw; __sincosf(-(TWO_PI_F / 8192.0f) * (float)k, &sw, &cw);
            float Tr = Or * cw - Oi * sw, Ti = Or * sw + Oi * cw;
            float Xkr = Er + Tr, Xki = Ei + Ti;
            float Xmr = Er - Tr, Xmi = Ti - Ei;
            float akr = res[(size_t)k * 1024 + c],  aki = res[(size_t)k * 1024 + c + 64];
            float amr = res[(size_t)km * 1024 + c], ami = res[(size_t)km * 1024 + c + 64];
            float Skr = akr * Xkr - aki * Xki, Ski = akr * Xki + aki * Xkr;
            float Smr = amr * Xmr - ami * Xmi, Smi = amr * Xmi + ami * Xmr;
            float Epr = 0.5f * (Skr + Smr), Epi = 0.5f * (Ski - Smi);
            float Ddr = 0.5f * (Skr - Smr), Ddi = 0.5f * (Ski + Smi);
            float Opr = Ddr * cw + Ddi * sw, Opi = Ddi * cw - Ddr * sw;
            re[sa] = Epr - Opi; im[sa] = Epi + Opr;
            re[sb] = Epr + Opi; im[sb] = Opr - Epi;
        }
    }
    __syncthreads();
    fft64_dit(re, im, col, 128, w8, 4, +1.0f, col < NC);

    const int nit2 = pairwg ? 16 : 8;
    for (int it = 0; it < nit2; ++it) {
        int item = it * 512 + tid;          // pl*4096 + m0*64 + d
        int pl = item >> 12, rem = item & 4095;
        int m0 = rem >> 6, d = rem & 63;
        int cc = pl * 64 + d;
        int k1 = pl ? k1b : k1a;
        float vr = re[m0 * 128 + cc], vi = im[m0 * 128 + cc];
        float ang = (TWO_PI_F / 4096.0f) * (float)(m0 * k1);
        float s, c2; __sincosf(ang, &s, &c2);
        U[(size_t)slab * 262144 + (size_t)m0 * 4096 + (size_t)k1 * 64 + d] =
            make_float2(vr * c2 - vi * s, vr * s + vi * c2);
    }
}

// ---------------------------------------------------------------------------
// Stage C: per (slab, m0): inverse FFT64 over k1 of U[m0][k1][d];
// z'[64m1+m0] lands at slot dr(m1); write out rows 2m, 2m+1 for m1<32.
// ---------------------------------------------------------------------------
__global__ __launch_bounds__(256) void inv2_kernel(const float2* __restrict__ U,
                                                   float* __restrict__ out)
{
    __shared__ float re[4096], im[4096];   // [k1 64][d 64]
    const int tid = threadIdx.x;
    const int m0 = blockIdx.x, slab = blockIdx.y;
    const float2* Us = U + (size_t)slab * 262144 + (size_t)m0 * 4096;
    for (int it = 0; it < 8; ++it) {
        int idx4 = it * 256 + tid;
        const float4 v = ((const float4*)Us)[idx4];
        int lin = idx4 * 2, k1 = lin >> 6, d = lin & 63;
        re[k1 * 64 + d] = v.x;     im[k1 * 64 + d] = v.y;
        re[k1 * 64 + d + 1] = v.z; im[k1 * 64 + d + 1] = v.w;
    }
    __syncthreads();
    const int d = tid & 63, w = tid >> 6;
    fft64_dif(re, im, d, 64, w, 4, +1.0f, true);
    float* os = out + (size_t)slab * 262144;
    const float sc = 1.0f / 4096.0f;
    for (int it = 0; it < 16; ++it) {
        int flat = it * 256 + tid;
        int m1 = flat >> 7, rr = (flat >> 6) & 1, dd = flat & 63;
        int slot = dr4_3(m1);
        float v = rr ? im[slot * 64 + dd] : re[slot * 64 + dd];
        os[(size_t)(128 * m1 + 2 * m0 + rr) * 64 + dd] = v * sc;
    }
}

// ===========================================================================
// Fallback path (round-1, verified): monolithic per-column kernel
// ===========================================================================
#define PADF(i) ((i) + ((i) >> 5))

__device__ __forceinline__ unsigned dr4_12(unsigned k) {
    unsigned rb = __brev(k) >> 20;
    return ((rb & 0x555u) << 1) | ((rb >> 1) & 0x555u);
}

__global__ __launch_bounds__(64) void rpe_mlp_kernel(
    const float* __restrict__ w_in, const float* __restrict__ b_in,
    const float* __restrict__ w_layers, const float* __restrict__ b_layers,
    const float* __restrict__ w_out, const float* __restrict__ b_out,
    float* __restrict__ res)
{
    const int k = blockIdx.x;
    const int lane = threadIdx.x;
    const float pos = PI_F * (float)k * (1.0f / 4096.0f);
    float xv = fmaf(pos, w_in[lane], b_in[lane]);
    for (int l = 0; l < 3; ++l) {
        float ss = xv * xv;
        #pragma unroll
        for (int o = 1; o < 64; o <<= 1) ss += __shfl_xor(ss, o, 64);
        float rms = sqrtf(ss * (1.0f / 64.0f));
        float r = xv / (rms + 1e-8f);
        r = r > 0.0f ? r : 0.0f;
        const float* W = w_layers + l * 64 * 64;
        float acc = b_layers[l * 64 + lane];
        for (int i = 0; i < 64; ++i)
            acc = fmaf(__shfl(r, i, 64), W[i * 64 + lane], acc);
        xv = acc;
    }
    float ss = xv * xv;
    #pragma unroll
    for (int o = 1; o < 64; o <<= 1) ss += __shfl_xor(ss, o, 64);
    float rms = sqrtf(ss * (1.0f / 64.0f));
    float r = xv / (rms + 1e-8f);
    r = r > 0.0f ? r : 0.0f;
    float acc[16];
    #pragma unroll
    for (int u = 0; u < 16; ++u) acc[u] = b_out[u * 64 + lane];
    for (int i = 0; i < 64; ++i) {
        float rv = __shfl(r, i, 64);
        const float* Wrow = w_out + i * 1024;
        #pragma unroll
        for (int u = 0; u < 16; ++u)
            acc[u] = fmaf(rv, Wrow[u * 64 + lane], acc[u]);
    }
    float* dst = res + (size_t)k * 1024;
    #pragma unroll
    for (int u = 0; u < 16; ++u) dst[u * 64 + lane] = acc[u];
}

__global__ __launch_bounds__(256) void fftconv_kernel(
    const float* __restrict__ x, const float* __restrict__ res,
    float* __restrict__ out)
{
    __shared__ float re[PADF(4095) + 1];
    __shared__ float im[PADF(4095) + 1];
    const int tid = threadIdx.x;
    const int blk = blockIdx.x;
    const int d = (blk >> 3) & 63;
    const int slab = (blk & 7) | ((blk >> 9) << 3);
    const int h = slab & 7;
    const size_t base = (size_t)slab * 4096 * 64 + (size_t)d;
    const float* xc = x + base;
    float* oc = out + base;
    const int c = h * 128 + d;
    for (int m = tid; m < 2048; m += 256) {
        re[PADF(m)] = xc[(size_t)(2 * m) * 64];
        im[PADF(m)] = xc[(size_t)(2 * m + 1) * 64];
    }
    for (int m = 2048 + tid; m < 4096; m += 256) { re[PADF(m)] = 0.0f; im[PADF(m)] = 0.0f; }
    __syncthreads();
    for (int S = 1024; S >= 1; S >>= 2) {
        const float ab = -TWO_PI_F / (float)(4 * S);
        for (int j = tid; j < 1024; j += 256) {
            const int q = j & (S - 1);
            const int i0 = ((j & ~(S - 1)) << 2) | q;
            const int p0 = PADF(i0), p1 = PADF(i0 + S), p2 = PADF(i0 + 2 * S), p3 = PADF(i0 + 3 * S);
            float x0r = re[p0], x0i = im[p0], x1r = re[p1], x1i = im[p1];
            float x2r = re[p2], x2i = im[p2], x3r = re[p3], x3i = im[p3];
            float A0r = x0r + x2r, A0i = x0i + x2i, A1r = x0r - x2r, A1i = x0i - x2i;
            float A2r = x1r + x3r, A2i = x1i + x3i, A3r = x1r - x3r, A3i = x1i - x3i;
            float s1, c1; __sincosf(ab * (float)q, &s1, &c1);
            float c2 = c1 * c1 - s1 * s1, s2 = 2.0f * c1 * s1;
            float c3 = c2 * c1 - s2 * s1, s3 = s2 * c1 + c2 * s1;
            re[p0] = A0r + A2r; im[p0] = A0i + A2i;
            float t1r = A1r + A3i, t1i = A1i - A3r;
            re[p1] = t1r * c1 - t1i * s1; im[p1] = t1r * s1 + t1i * c1;
            float t2r = A0r - A2r, t2i = A0i - A2i;
            re[p2] = t2r * c2 - t2i * s2; im[p2] = t2r * s2 + t2i * c2;
            float t3r = A1r - A3i, t3i = A1i + A3r;
            re[p3] = t3r * c3 - t3i * s3; im[p3] = t3r * s3 + t3i * c3;
        }
        __syncthreads();
    }
    for (int k = tid; k <= 2048; k += 256) {
        if (k == 0) {
            float C0r = re[0], C0i = im[0];
            float X0 = C0r + C0i, XN = C0r - C0i;
            float a0 = res[c], aN = res[(size_t)4096 * 1024 + c];
            float S0 = a0 * X0, SN = aN * XN;
            re[0] = 0.5f * (S0 + SN); im[0] = 0.5f * (S0 - SN);
        } else if (k == 2048) {
            const int p = PADF(2);
            float Cr = re[p], Ci = im[p];
            float ar = res[(size_t)2048 * 1024 + c], ai = res[(size_t)2048 * 1024 + c + 64];
            float Sr = ar * Cr + ai * Ci, Si = ai * Cr - ar * Ci;
            re[p] = Sr; im[p] = -Si;
        } else {
            const int pk = PADF((int)dr4_12((unsigned)k));
            const int pm = PADF((int)dr4_12((unsigned)(4096 - k)));
            float Ckr = re[pk], Cki = im[pk];
            float Cmr = re[pm], Cmi = im[pm];
            float Er = 0.5f * (Ckr + Cmr), Ei = 0.5f * (Cki - Cmi);
            float Dr = 0.5f * (Ckr - Cmr), Di = 0.5f * (Cki + Cmi);
            float Or = Di, Oi = -Dr;
            float sw, cw; __sincosf(-TWO_PI_F * (float)k * (1.0f / 8192.0f), &sw, &cw);
            float Tr = Or * cw - Oi * sw, Ti = Or * sw + Oi * cw;
            float Xkr = Er + Tr, Xki = Ei + Ti;
            float Xmr = Er - Tr, Xmi = Ti - Ei;
            float akr = res[(size_t)k * 1024 + c], aki = res[(size_t)k * 1024 + c + 64];
            float amr = res[(size_t)(4096 - k) * 1024 + c], ami = res[(size_t)(4096 - k) * 1024 + c + 64];
            float Skr = akr * Xkr - aki * Xki, Ski = akr * Xki + aki * Xkr;
            float Smr = amr * Xmr - ami * Xmi, Smi = amr * Xmi + ami * Xmr;
            float Epr = 0.5f * (Skr + Smr), Epi = 0.5f * (Ski - Smi);
            float Ddr = 0.5f * (Skr - Smr), Ddi = 0.5f * (Ski + Smi);
            float Opr = Ddr * cw + Ddi * sw, Opi = Ddi * cw - Ddr * sw;
            re[pk] = Epr - Opi; im[pk] = Epi + Opr;
            re[pm] = Epr + Opi; im[pm] = Opr - Epi;
        }
    }
    __syncthreads();
    for (int S = 1; S <= 1024; S <<= 2) {
        const float ab = TWO_PI_F / (float)(4 * S);
        for (int j = tid; j < 1024; j += 256) {
            const int q = j & (S - 1);
            const int i0 = ((j & ~(S - 1)) << 2) | q;
            const int p0 = PADF(i0), p1 = PADF(i0 + S), p2 = PADF(i0 + 2 * S), p3 = PADF(i0 + 3 * S);
            float y0r = re[p0], y0i = im[p0], y1r = re[p1], y1i = im[p1];
            float y2r = re[p2], y2i = im[p2], y3r = re[p3], y3i = im[p3];
            float s1, c1; __sincosf(ab * (float)q, &s1, &c1);
            float c2 = c1 * c1 - s1 * s1, s2 = 2.0f * c1 * s1;
            float c3 = c2 * c1 - s2 * s1, s3 = s2 * c1 + c2 * s1;
            float x1r = y1r * c1 - y1i * s1, x1i = y1r * s1 + y1i * c1;
            float x2r = y2r * c2 - y2i * s2, x2i = y2r * s2 + y2i * c2;
            float x3r = y3r * c3 - y3i * s3, x3i = y3r * s3 + y3i * c3;
            float B0r = y0r + x2r, B0i = y0i + x2i, B1r = y0r - x2r, B1i = y0i - x2i;
            float B2r = x1r + x3r, B2i = x1i + x3i, B3r = x1r - x3r, B3i = x1i - x3i;
            re[p0] = B0r + B2r; im[p0] = B0i + B2i;
            re[p1] = B1r - B3i; im[p1] = B1i + B3r;
            re[p2] = B0r - B2r; im[p2] = B0i - B2i;
            re[p3] = B1r + B3i; im[p3] = B1i - B3r;
        }
        __syncthreads();
    }
    const float sc = 1.0f / 4096.0f;
    for (int m = tid; m < 2048; m += 256) {
        oc[(size_t)(2 * m) * 64]     = re[PADF(m)] * sc;
        oc[(size_t)(2 * m + 1) * 64] = im[PADF(m)] * sc;
    }
}

// ---------------------------------------------------------------------------
extern "C" void kernel_launch(void* const* d_in, const int* in_sizes, int n_in,
                              void* d_out, int out_size, void* d_ws, size_t ws_size,
                              hipStream_t stream) {
    const float* x        = (const float*)d_in[0];
    const float* w_in     = (const float*)d_in[1];
    const float* b_in     = (const float*)d_in[2];
    const float* w_layers = (const float*)d_in[3];
    const float* b_layers = (const float*)d_in[4];
    const float* w_out    = (const float*)d_in[5];
    const float* b_out    = (const float*)d_in[6];
    float* out = (float*)d_out;
    float* wsf = (float*)d_ws;

    // ws layout (floats): res[4097*1024] | r[4097*64] | Y[64*64*64*64*2] | U[same]
    const size_t off_res = 0;
    const size_t off_r   = 4195328;              // 4097*1024
    const size_t off_Y   = 4457536;              // + 4097*64 (16B-aligned)
    const size_t off_U   = off_Y + 33554432;     // + 64*4096*64*2
    const size_t need_bytes = (off_U + 33554432) * sizeof(float);   // 286,265,600

    float* res = wsf + off_res;
    if (ws_size >= need_bytes) {
        mlp_hidden_kernel<<<1025, 256, 0, stream>>>(w_in, b_in, w_layers, b_layers,
                                                    wsf + off_r);
        mlp_out_kernel<<<dim3(4, 257), 256, 0, stream>>>(wsf + off_r, w_out, b_out, res);
        fwd1_kernel<<<dim3(64, 64), 256, 0, stream>>>(x, (float2*)(wsf + off_Y));
        midspec_kernel<<<dim3(33, 64), 512, 0, stream>>>((const float2*)(wsf + off_Y),
                                                         res, (float2*)(wsf + off_U));
        inv2_kernel<<<dim3(64, 64), 256, 0, stream>>>((const float2*)(wsf + off_U), out);
    } else {
        rpe_mlp_kernel<<<4097, 64, 0, stream>>>(w_in, b_in, w_layers, b_layers,
                                                w_out, b_out, res);
        fftconv_kernel<<<4096, 256, 0, stream>>>(x, res, out);
    }
}

// Round 4
// 274.771 us; speedup vs baseline: 1.4546x; 1.4449x over previous
//
#include <hip/hip_runtime.h>
#include <math.h>

// B=8, H=8, N=4096, D=64 ; fft_size=8192, nf=4097 ; packed complex FFT M=4096
// Four-step: 4096 = 64 x 64.  m = 64*m1 + m0,  k = 64*k0 + k1.
// Scratch-lean version: stage B (midspec) is IN-PLACE on Y (each block owns
// planes {k1, 64-k1}), and slabs are processed in chunks sized from ws_size.

#define PI_F 3.14159265358979323846f
#define TWO_PI_F 6.283185307179586f

__device__ __forceinline__ int dr4_3(int k) {   // 3-digit base-4 reverse
    return ((k & 3) << 4) | (k & 12) | ((k >> 4) & 3);
}

// 64-pt radix-4 DIF over row index (natural in -> digit-reversed out).
// sgn=-1 forward (e^{-i}), sgn=+1 inverse. col < ncol selects batch column.
__device__ __forceinline__ void fft64_dif(float* re, float* im, int col, int ncol,
                                          int w, int nw, float sgn, bool act) {
    for (int S = 16; S >= 1; S >>= 2) {
        const float ab = sgn * TWO_PI_F / (float)(4 * S);
        if (act) {
            for (int j = w; j < 16; j += nw) {
                const int q = j & (S - 1);
                const int i0 = ((j & ~(S - 1)) << 2) | q;
                const int p0 = i0 * ncol + col, p1 = (i0 + S) * ncol + col;
                const int p2 = (i0 + 2 * S) * ncol + col, p3 = (i0 + 3 * S) * ncol + col;
                float x0r = re[p0], x0i = im[p0], x1r = re[p1], x1i = im[p1];
                float x2r = re[p2], x2i = im[p2], x3r = re[p3], x3i = im[p3];
                float A0r = x0r + x2r, A0i = x0i + x2i, A1r = x0r - x2r, A1i = x0i - x2i;
                float A2r = x1r + x3r, A2i = x1i + x3i, A3r = x1r - x3r, A3i = x1i - x3i;
                float s1, c1; __sincosf(ab * (float)q, &s1, &c1);
                float c2 = c1 * c1 - s1 * s1, s2 = 2.0f * c1 * s1;
                float c3 = c2 * c1 - s2 * s1, s3 = s2 * c1 + c2 * s1;
                re[p0] = A0r + A2r; im[p0] = A0i + A2i;
                float t1r = A1r - sgn * A3i, t1i = A1i + sgn * A3r;   // A1 + sgn*i*A3
                re[p1] = t1r * c1 - t1i * s1; im[p1] = t1r * s1 + t1i * c1;
                float t2r = A0r - A2r, t2i = A0i - A2i;
                re[p2] = t2r * c2 - t2i * s2; im[p2] = t2r * s2 + t2i * c2;
                float t3r = A1r + sgn * A3i, t3i = A1i - sgn * A3r;   // A1 - sgn*i*A3
                re[p3] = t3r * c3 - t3i * s3; im[p3] = t3r * s3 + t3i * c3;
            }
        }
        __syncthreads();
    }
}

// 64-pt radix-4 DIT (digit-reversed in -> natural out), sgn as above.
__device__ __forceinline__ void fft64_dit(float* re, float* im, int col, int ncol,
                                          int w, int nw, float sgn, bool act) {
    for (int S = 1; S <= 16; S <<= 2) {
        const float ab = sgn * TWO_PI_F / (float)(4 * S);
        if (act) {
            for (int j = w; j < 16; j += nw) {
                const int q = j & (S - 1);
                const int i0 = ((j & ~(S - 1)) << 2) | q;
                const int p0 = i0 * ncol + col, p1 = (i0 + S) * ncol + col;
                const int p2 = (i0 + 2 * S) * ncol + col, p3 = (i0 + 3 * S) * ncol + col;
                float y0r = re[p0], y0i = im[p0], y1r = re[p1], y1i = im[p1];
                float y2r = re[p2], y2i = im[p2], y3r = re[p3], y3i = im[p3];
                float s1, c1; __sincosf(ab * (float)q, &s1, &c1);
                float c2 = c1 * c1 - s1 * s1, s2 = 2.0f * c1 * s1;
                float c3 = c2 * c1 - s2 * s1, s3 = s2 * c1 + c2 * s1;
                float x1r = y1r * c1 - y1i * s1, x1i = y1r * s1 + y1i * c1;
                float x2r = y2r * c2 - y2i * s2, x2i = y2r * s2 + y2i * c2;
                float x3r = y3r * c3 - y3i * s3, x3i = y3r * s3 + y3i * c3;
                float B0r = y0r + x2r, B0i = y0i + x2i, B1r = y0r - x2r, B1i = y0i - x2i;
                float B2r = x1r + x3r, B2i = x1i + x3i, B3r = x1r - x3r, B3i = x1i - x3i;
                re[p0] = B0r + B2r; im[p0] = B0i + B2i;
                re[p1] = B1r - sgn * B3i; im[p1] = B1i + sgn * B3r;   // B1 + sgn*i*B3
                re[p2] = B0r - B2r; im[p2] = B0i - B2i;
                re[p3] = B1r + sgn * B3i; im[p3] = B1i - sgn * B3r;   // B1 - sgn*i*B3
            }
        }
        __syncthreads();
    }
}

// ---------------------------------------------------------------------------
// MLP stage 1: hidden activations r[k][64] (post relu(srms) of layer 3).
// ---------------------------------------------------------------------------
__global__ __launch_bounds__(256) void mlp_hidden_kernel(
    const float* __restrict__ w_in, const float* __restrict__ b_in,
    const float* __restrict__ w_layers, const float* __restrict__ b_layers,
    float* __restrict__ rbuf)
{
    const int lane = threadIdx.x & 63;
    const int k = blockIdx.x * 4 + (threadIdx.x >> 6);
    if (k > 4096) return;
    const float pos = PI_F * (float)k * (1.0f / 4096.0f);
    float xv = fmaf(pos, w_in[lane], b_in[lane]);
    for (int l = 0; l < 3; ++l) {
        float ss = xv * xv;
        #pragma unroll
        for (int o = 1; o < 64; o <<= 1) ss += __shfl_xor(ss, o, 64);
        float r = xv / (sqrtf(ss * (1.0f / 64.0f)) + 1e-8f);
        r = fmaxf(r, 0.0f);
        const float* W = w_layers + l * 4096;
        float a0 = 0.f, a1 = 0.f, a2 = 0.f, a3 = 0.f;
        for (int i = 0; i < 64; i += 4) {
            a0 = fmaf(__shfl(r, i, 64),     W[(i) * 64 + lane],     a0);
            a1 = fmaf(__shfl(r, i + 1, 64), W[(i + 1) * 64 + lane], a1);
            a2 = fmaf(__shfl(r, i + 2, 64), W[(i + 2) * 64 + lane], a2);
            a3 = fmaf(__shfl(r, i + 3, 64), W[(i + 3) * 64 + lane], a3);
        }
        xv = ((a0 + a1) + (a2 + a3)) + b_layers[l * 64 + lane];
    }
    float ss = xv * xv;
    #pragma unroll
    for (int o = 1; o < 64; o <<= 1) ss += __shfl_xor(ss, o, 64);
    float r = xv / (sqrtf(ss * (1.0f / 64.0f)) + 1e-8f);
    r = fmaxf(r, 0.0f);
    rbuf[(size_t)k * 64 + lane] = r;
}

// ---------------------------------------------------------------------------
// MLP stage 2: res[4097][1024] = r @ w_out + b_out.
// ---------------------------------------------------------------------------
__global__ __launch_bounds__(256) void mlp_out_kernel(
    const float* __restrict__ rbuf, const float* __restrict__ w_out,
    const float* __restrict__ b_out, float* __restrict__ res)
{
    __shared__ float rl[16 * 64];
    const int tid = threadIdx.x;
    const int nt = blockIdx.x, kt = blockIdx.y;   // nt 0..3, kt 0..256
    for (int it = 0; it < 4; ++it) {
        int idx = it * 256 + tid;
        int row = idx >> 6, i = idx & 63;
        int k = kt * 16 + row;
        rl[idx] = (k <= 4096) ? rbuf[(size_t)k * 64 + i] : 0.0f;
    }
    __syncthreads();
    const int n = nt * 256 + tid;
    float acc[16];
    #pragma unroll
    for (int j = 0; j < 16; ++j) acc[j] = 0.0f;
    for (int i = 0; i < 64; ++i) {
        float wv = w_out[(size_t)i * 1024 + n];
        #pragma unroll
        for (int j = 0; j < 16; ++j)
            acc[j] = fmaf(rl[j * 64 + i], wv, acc[j]);
    }
    float bv = b_out[n];
    for (int j = 0; j < 16; ++j) {
        int k = kt * 16 + j;
        if (k <= 4096) res[(size_t)k * 1024 + n] = acc[j] + bv;
    }
}

// ---------------------------------------------------------------------------
// Stage A: per (lslab, m0): FFT64 over m1 of z[64m1+m0][d] (m1>=32 zero),
// times W4096^{-m0*k1}; write Y[lslab][k1][m0][d] (float2).
// ---------------------------------------------------------------------------
__global__ __launch_bounds__(256) void fwd1_kernel(const float* __restrict__ x,
                                                   float2* __restrict__ Y,
                                                   int slab_base)
{
    __shared__ float re[4096], im[4096];   // [m1 64][d 64]
    const int tid = threadIdx.x;
    const int m0 = blockIdx.x, lslab = blockIdx.y;
    const float* xs = x + (size_t)(slab_base + lslab) * 262144;
    for (int it = 0; it < 16; ++it) {
        int flat = it * 256 + tid;
        int m1 = flat >> 7, rr = (flat >> 6) & 1, d = flat & 63;
        float v = xs[(size_t)(128 * m1 + 2 * m0 + rr) * 64 + d];
        if (rr == 0) re[m1 * 64 + d] = v; else im[m1 * 64 + d] = v;
    }
    for (int i = 2048 + tid; i < 4096; i += 256) { re[i] = 0.0f; im[i] = 0.0f; }
    __syncthreads();
    const int d = tid & 63, w = tid >> 6;
    fft64_dif(re, im, d, 64, w, 4, -1.0f, true);
    float2* Ys = Y + (size_t)lslab * 262144 + (size_t)m0 * 64;
    for (int og = 0; og < 16; ++og) {
        int k1 = og * 4 + w;
        int slot = dr4_3(k1);
        float vr = re[slot * 64 + d], vi = im[slot * 64 + d];
        float ang = -(TWO_PI_F / 4096.0f) * (float)(m0 * k1);
        float s, c; __sincosf(ang, &s, &c);
        Ys[(size_t)k1 * 4096 + d] = make_float2(vr * c - vi * s, vr * s + vi * c);
    }
}

// ---------------------------------------------------------------------------
// Stage B (IN-PLACE on Y): per (lslab, k1-pair): FFT64 over m0 -> C[64k0+k1];
// spectral unpack * filter * repack on pairs (k, 4096-k); inverse FFT64 over
// k0; times W4096^{+m0*k1}; write back to Y[lslab][k1][m0][d].
// ---------------------------------------------------------------------------
__global__ __launch_bounds__(512) void midspec_kernel(float2* __restrict__ Y,
                                                      const float* __restrict__ res,
                                                      int slab_base)
{
    __shared__ float re[8192], im[8192];   // [row 64][col 128]: colA=[0,64) colB=[64,128)
    const int tid = threadIdx.x;
    const int k1p = blockIdx.x;            // 0..32
    const int lslab = blockIdx.y;
    const int h = (slab_base + lslab) & 7;
    const bool pairwg = (k1p >= 1 && k1p <= 31);
    const int k1a = k1p;
    const int k1b = pairwg ? (64 - k1p) : k1p;
    const int NC = pairwg ? 128 : 64;

    const float2* Pa = Y + (size_t)lslab * 262144 + (size_t)k1a * 4096;
    for (int it = 0; it < 4; ++it) {
        int idx4 = it * 512 + tid;
        const float4 v = ((const float4*)Pa)[idx4];
        int lin = idx4 * 2, m0 = lin >> 6, d = lin & 63;
        re[m0 * 128 + d] = v.x;     im[m0 * 128 + d] = v.y;
        re[m0 * 128 + d + 1] = v.z; im[m0 * 128 + d + 1] = v.w;
    }
    if (pairwg) {
        const float2* Pb = Y + (size_t)lslab * 262144 + (size_t)k1b * 4096;
        for (int it = 0; it < 4; ++it) {
            int idx4 = it * 512 + tid;
            const float4 v = ((const float4*)Pb)[idx4];
            int lin = idx4 * 2, m0 = lin >> 6, d = lin & 63;
            re[m0 * 128 + 64 + d] = v.x;     im[m0 * 128 + 64 + d] = v.y;
            re[m0 * 128 + 64 + d + 1] = v.z; im[m0 * 128 + 64 + d + 1] = v.w;
        }
    }
    __syncthreads();
    const int col = tid & 127, w8 = tid >> 7;
    fft64_dif(re, im, col, 128, w8, 4, -1.0f, col < NC);

    // spectral multiply on conjugate-pairs; each slot touched exactly once
    const int nit = pairwg ? 8 : 4;
    for (int it = 0; it < nit; ++it) {
        int item = it * 512 + tid;         // k0*64 + d
        int k0 = item >> 6, d = item & 63;
        int c = h * 128 + d;
        if (k1p == 0 && k0 == 0) {
            float C0r = re[d], C0i = im[d];                 // slot dr(0)=0
            float X0 = C0r + C0i, XN = C0r - C0i;
            float a0 = res[c], aN = res[(size_t)4096 * 1024 + c];
            float S0 = a0 * X0, SN = aN * XN;
            re[d] = 0.5f * (S0 + SN); im[d] = 0.5f * (S0 - SN);
            int p2 = 2 * 128 + d;                           // slot dr(32)=2
            float Cr = re[p2], Ci = im[p2];
            float ar = res[(size_t)2048 * 1024 + c], ai = res[(size_t)2048 * 1024 + c + 64];
            float Sr = ar * Cr + ai * Ci, Si = ai * Cr - ar * Ci;
            re[p2] = Sr; im[p2] = -Si;
        } else {
            int k0p, coff;
            if (pairwg)          { k0p = 63 - k0;        coff = 64; }
            else if (k1p == 0)   { k0p = (64 - k0) & 63; coff = 0;  }
            else /* k1p == 32 */ { k0p = 63 - k0;        coff = 0;  }
            int sa = dr4_3(k0)  * 128 + d;
            int sb = dr4_3(k0p) * 128 + coff + d;
            int k  = k0 * 64 + k1a;
            int km = 4096 - k;
            float Ckr = re[sa], Cki = im[sa];
            float Cmr = re[sb], Cmi = im[sb];
            float Er = 0.5f * (Ckr + Cmr), Ei = 0.5f * (Cki - Cmi);
            float Dr = 0.5f * (Ckr - Cmr), Di = 0.5f * (Cki + Cmi);
            float Or = Di, Oi = -Dr;
            float sw, cw; __sincosf(-(TWO_PI_F / 8192.0f) * (float)k, &sw, &cw);
            float Tr = Or * cw - Oi * sw, Ti = Or * sw + Oi * cw;
            float Xkr = Er + Tr, Xki = Ei + Ti;
            float Xmr = Er - Tr, Xmi = Ti - Ei;
            float akr = res[(size_t)k * 1024 + c],  aki = res[(size_t)k * 1024 + c + 64];
            float amr = res[(size_t)km * 1024 + c], ami = res[(size_t)km * 1024 + c + 64];
            float Skr = akr * Xkr - aki * Xki, Ski = akr * Xki + aki * Xkr;
            float Smr = amr * Xmr - ami * Xmi, Smi = amr * Xmi + ami * Xmr;
            float Epr = 0.5f * (Skr + Smr), Epi = 0.5f * (Ski - Smi);
            float Ddr = 0.5f * (Skr - Smr), Ddi = 0.5f * (Ski + Smi);
            float Opr = Ddr * cw + Ddi * sw, Opi = Ddi * cw - Ddr * sw;
            re[sa] = Epr - Opi; im[sa] = Epi + Opr;
            re[sb] = Epr + Opi; im[sb] = Opr - Epi;
        }
    }
    __syncthreads();
    fft64_dit(re, im, col, 128, w8, 4, +1.0f, col < NC);

    // write back IN-PLACE to the same Y planes this block loaded
    const int nit2 = pairwg ? 16 : 8;
    for (int it = 0; it < nit2; ++it) {
        int item = it * 512 + tid;          // pl*4096 + m0*64 + d
        int pl = item >> 12, rem = item & 4095;
        int m0 = rem >> 6, d = rem & 63;
        int cc = pl * 64 + d;
        int k1 = pl ? k1b : k1a;
        float vr = re[m0 * 128 + cc], vi = im[m0 * 128 + cc];
        float ang = (TWO_PI_F / 4096.0f) * (float)(m0 * k1);
        float s, c2; __sincosf(ang, &s, &c2);
        Y[(size_t)lslab * 262144 + (size_t)k1 * 4096 + (size_t)m0 * 64 + d] =
            make_float2(vr * c2 - vi * s, vr * s + vi * c2);
    }
}

// ---------------------------------------------------------------------------
// Stage C: per (lslab, m0): inverse FFT64 over k1 of Y[k1][m0][d];
// z'[64m1+m0] lands at slot dr(m1); write out rows 2m, 2m+1 for m1<32.
// ---------------------------------------------------------------------------
__global__ __launch_bounds__(256) void inv2_kernel(const float2* __restrict__ Y,
                                                   float* __restrict__ out,
                                                   int slab_base)
{
    __shared__ float re[4096], im[4096];   // [k1 64][d 64]
    const int tid = threadIdx.x;
    const int m0 = blockIdx.x, lslab = blockIdx.y;
    const float2* Ys = Y + (size_t)lslab * 262144 + (size_t)m0 * 64;
    for (int it = 0; it < 8; ++it) {
        int idx4 = it * 256 + tid;              // 0..2047
        int lin = idx4 * 2, k1 = lin >> 6, d = lin & 63;
        const float4 v = ((const float4*)Ys)[k1 * 2048 + (d >> 1)];
        re[k1 * 64 + d] = v.x;     im[k1 * 64 + d] = v.y;
        re[k1 * 64 + d + 1] = v.z; im[k1 * 64 + d + 1] = v.w;
    }
    __syncthreads();
    const int d = tid & 63, w = tid >> 6;
    fft64_dif(re, im, d, 64, w, 4, +1.0f, true);
    float* os = out + (size_t)(slab_base + lslab) * 262144;
    const float sc = 1.0f / 4096.0f;
    for (int it = 0; it < 16; ++it) {
        int flat = it * 256 + tid;
        int m1 = flat >> 7, rr = (flat >> 6) & 1, dd = flat & 63;
        int slot = dr4_3(m1);
        float v = rr ? im[slot * 64 + dd] : re[slot * 64 + dd];
        os[(size_t)(128 * m1 + 2 * m0 + rr) * 64 + dd] = v * sc;
    }
}

// ===========================================================================
// Fallback path (round-1, verified): monolithic per-column kernel
// ===========================================================================
#define PADF(i) ((i) + ((i) >> 5))

__device__ __forceinline__ unsigned dr4_12(unsigned k) {
    unsigned rb = __brev(k) >> 20;
    return ((rb & 0x555u) << 1) | ((rb >> 1) & 0x555u);
}

__global__ __launch_bounds__(64) void rpe_mlp_kernel(
    const float* __restrict__ w_in, const float* __restrict__ b_in,
    const float* __restrict__ w_layers, const float* __restrict__ b_layers,
    const float* __restrict__ w_out, const float* __restrict__ b_out,
    float* __restrict__ res)
{
    const int k = blockIdx.x;
    const int lane = threadIdx.x;
    const float pos = PI_F * (float)k * (1.0f / 4096.0f);
    float xv = fmaf(pos, w_in[lane], b_in[lane]);
    for (int l = 0; l < 3; ++l) {
        float ss = xv * xv;
        #pragma unroll
        for (int o = 1; o < 64; o <<= 1) ss += __shfl_xor(ss, o, 64);
        float rms = sqrtf(ss * (1.0f / 64.0f));
        float r = xv / (rms + 1e-8f);
        r = r > 0.0f ? r : 0.0f;
        const float* W = w_layers + l * 64 * 64;
        float acc = b_layers[l * 64 + lane];
        for (int i = 0; i < 64; ++i)
            acc = fmaf(__shfl(r, i, 64), W[i * 64 + lane], acc);
        xv = acc;
    }
    float ss = xv * xv;
    #pragma unroll
    for (int o = 1; o < 64; o <<= 1) ss += __shfl_xor(ss, o, 64);
    float rms = sqrtf(ss * (1.0f / 64.0f));
    float r = xv / (rms + 1e-8f);
    r = r > 0.0f ? r : 0.0f;
    float acc[16];
    #pragma unroll
    for (int u = 0; u < 16; ++u) acc[u] = b_out[u * 64 + lane];
    for (int i = 0; i < 64; ++i) {
        float rv = __shfl(r, i, 64);
        const float* Wrow = w_out + i * 1024;
        #pragma unroll
        for (int u = 0; u < 16; ++u)
            acc[u] = fmaf(rv, Wrow[u * 64 + lane], acc[u]);
    }
    float* dst = res + (size_t)k * 1024;
    #pragma unroll
    for (int u = 0; u < 16; ++u) dst[u * 64 + lane] = acc[u];
}

__global__ __launch_bounds__(256) void fftconv_kernel(
    const float* __restrict__ x, const float* __restrict__ res,
    float* __restrict__ out)
{
    __shared__ float re[PADF(4095) + 1];
    __shared__ float im[PADF(4095) + 1];
    const int tid = threadIdx.x;
    const int blk = blockIdx.x;
    const int d = (blk >> 3) & 63;
    const int slab = (blk & 7) | ((blk >> 9) << 3);
    const int h = slab & 7;
    const size_t base = (size_t)slab * 4096 * 64 + (size_t)d;
    const float* xc = x + base;
    float* oc = out + base;
    const int c = h * 128 + d;
    for (int m = tid; m < 2048; m += 256) {
        re[PADF(m)] = xc[(size_t)(2 * m) * 64];
        im[PADF(m)] = xc[(size_t)(2 * m + 1) * 64];
    }
    for (int m = 2048 + tid; m < 4096; m += 256) { re[PADF(m)] = 0.0f; im[PADF(m)] = 0.0f; }
    __syncthreads();
    for (int S = 1024; S >= 1; S >>= 2) {
        const float ab = -TWO_PI_F / (float)(4 * S);
        for (int j = tid; j < 1024; j += 256) {
            const int q = j & (S - 1);
            const int i0 = ((j & ~(S - 1)) << 2) | q;
            const int p0 = PADF(i0), p1 = PADF(i0 + S), p2 = PADF(i0 + 2 * S), p3 = PADF(i0 + 3 * S);
            float x0r = re[p0], x0i = im[p0], x1r = re[p1], x1i = im[p1];
            float x2r = re[p2], x2i = im[p2], x3r = re[p3], x3i = im[p3];
            float A0r = x0r + x2r, A0i = x0i + x2i, A1r = x0r - x2r, A1i = x0i - x2i;
            float A2r = x1r + x3r, A2i = x1i + x3i, A3r = x1r - x3r, A3i = x1i - x3i;
            float s1, c1; __sincosf(ab * (float)q, &s1, &c1);
            float c2 = c1 * c1 - s1 * s1, s2 = 2.0f * c1 * s1;
            float c3 = c2 * c1 - s2 * s1, s3 = s2 * c1 + c2 * s1;
            re[p0] = A0r + A2r; im[p0] = A0i + A2i;
            float t1r = A1r + A3i, t1i = A1i - A3r;
            re[p1] = t1r * c1 - t1i * s1; im[p1] = t1r * s1 + t1i * c1;
            float t2r = A0r - A2r, t2i = A0i - A2i;
            re[p2] = t2r * c2 - t2i * s2; im[p2] = t2r * s2 + t2i * c2;
            float t3r = A1r - A3i, t3i = A1i + A3r;
            re[p3] = t3r * c3 - t3i * s3; im[p3] = t3r * s3 + t3i * c3;
        }
        __syncthreads();
    }
    for (int k = tid; k <= 2048; k += 256) {
        if (k == 0) {
            float C0r = re[0], C0i = im[0];
            float X0 = C0r + C0i, XN = C0r - C0i;
            float a0 = res[c], aN = res[(size_t)4096 * 1024 + c];
            float S0 = a0 * X0, SN = aN * XN;
            re[0] = 0.5f * (S0 + SN); im[0] = 0.5f * (S0 - SN);
        } else if (k == 2048) {
            const int p = PADF(2);
            float Cr = re[p], Ci = im[p];
            float ar = res[(size_t)2048 * 1024 + c], ai = res[(size_t)2048 * 1024 + c + 64];
            float Sr = ar * Cr + ai * Ci, Si = ai * Cr - ar * Ci;
            re[p] = Sr; im[p] = -Si;
        } else {
            const int pk = PADF((int)dr4_12((unsigned)k));
            const int pm = PADF((int)dr4_12((unsigned)(4096 - k)));
            float Ckr = re[pk], Cki = im[pk];
            float Cmr = re[pm], Cmi = im[pm];
            float Er = 0.5f * (Ckr + Cmr), Ei = 0.5f * (Cki - Cmi);
            float Dr = 0.5f * (Ckr - Cmr), Di = 0.5f * (Cki + Cmi);
            float Or = Di, Oi = -Dr;
            float sw, cw; __sincosf(-TWO_PI_F * (float)k * (1.0f / 8192.0f), &sw, &cw);
            float Tr = Or * cw - Oi * sw, Ti = Or * sw + Oi * cw;
            float Xkr = Er + Tr, Xki = Ei + Ti;
            float Xmr = Er - Tr, Xmi = Ti - Ei;
            float akr = res[(size_t)k * 1024 + c], aki = res[(size_t)k * 1024 + c + 64];
            float amr = res[(size_t)(4096 - k) * 1024 + c], ami = res[(size_t)(4096 - k) * 1024 + c + 64];
            float Skr = akr * Xkr - aki * Xki, Ski = akr * Xki + aki * Xkr;
            float Smr = amr * Xmr - ami * Xmi, Smi = amr * Xmi + ami * Xmr;
            float Epr = 0.5f * (Skr + Smr), Epi = 0.5f * (Ski - Smi);
            float Ddr = 0.5f * (Skr - Smr), Ddi = 0.5f * (Ski + Smi);
            float Opr = Ddr * cw + Ddi * sw, Opi = Ddi * cw - Ddr * sw;
            re[pk] = Epr - Opi; im[pk] = Epi + Opr;
            re[pm] = Epr + Opi; im[pm] = Opr - Epi;
        }
    }
    __syncthreads();
    for (int S = 1; S <= 1024; S <<= 2) {
        const float ab = TWO_PI_F / (float)(4 * S);
        for (int j = tid; j < 1024; j += 256) {
            const int q = j & (S - 1);
            const int i0 = ((j & ~(S - 1)) << 2) | q;
            const int p0 = PADF(i0), p1 = PADF(i0 + S), p2 = PADF(i0 + 2 * S), p3 = PADF(i0 + 3 * S);
            float y0r = re[p0], y0i = im[p0], y1r = re[p1], y1i = im[p1];
            float y2r = re[p2], y2i = im[p2], y3r = re[p3], y3i = im[p3];
            float s1, c1; __sincosf(ab * (float)q, &s1, &c1);
            float c2 = c1 * c1 - s1 * s1, s2 = 2.0f * c1 * s1;
            float c3 = c2 * c1 - s2 * s1, s3 = s2 * c1 + c2 * s1;
            float x1r = y1r * c1 - y1i * s1, x1i = y1r * s1 + y1i * c1;
            float x2r = y2r * c2 - y2i * s2, x2i = y2r * s2 + y2i * c2;
            float x3r = y3r * c3 - y3i * s3, x3i = y3r * s3 + y3i * c3;
            float B0r = y0r + x2r, B0i = y0i + x2i, B1r = y0r - x2r, B1i = y0i - x2i;
            float B2r = x1r + x3r, B2i = x1i + x3i, B3r = x1r - x3r, B3i = x1i - x3i;
            re[p0] = B0r + B2r; im[p0] = B0i + B2i;
            re[p1] = B1r - B3i; im[p1] = B1i + B3r;
            re[p2] = B0r - B2r; im[p2] = B0i - B2i;
            re[p3] = B1r + B3i; im[p3] = B1i - B3r;
        }
        __syncthreads();
    }
    const float sc = 1.0f / 4096.0f;
    for (int m = tid; m < 2048; m += 256) {
        oc[(size_t)(2 * m) * 64]     = re[PADF(m)] * sc;
        oc[(size_t)(2 * m + 1) * 64] = im[PADF(m)] * sc;
    }
}

// ---------------------------------------------------------------------------
extern "C" void kernel_launch(void* const* d_in, const int* in_sizes, int n_in,
                              void* d_out, int out_size, void* d_ws, size_t ws_size,
                              hipStream_t stream) {
    const float* x        = (const float*)d_in[0];
    const float* w_in     = (const float*)d_in[1];
    const float* b_in     = (const float*)d_in[2];
    const float* w_layers = (const float*)d_in[3];
    const float* b_layers = (const float*)d_in[4];
    const float* w_out    = (const float*)d_in[5];
    const float* b_out    = (const float*)d_in[6];
    float* out = (float*)d_out;
    float* wsf = (float*)d_ws;

    // ws layout (floats): res[4097*1024] | r[4097*64] | Y[nc * 64*64*64 * 2]
    const size_t off_res = 0;
    const size_t off_r   = 4195328;              // 4097*1024
    const size_t off_Y   = 4457536;              // + 4097*64   (16B aligned)
    const size_t Y_PER_SLAB = 524288;            // floats (2 MB) per slab

    float* res = wsf + off_res;
    const size_t avail_f = ws_size / 4;
    int nc = 0;
    if (avail_f > off_Y)
        nc = (int)((avail_f - off_Y) / Y_PER_SLAB);
    if (nc > 64) nc = 64;

    if (nc >= 1) {
        float2* Y = (float2*)(wsf + off_Y);
        mlp_hidden_kernel<<<1025, 256, 0, stream>>>(w_in, b_in, w_layers, b_layers,
                                                    wsf + off_r);
        mlp_out_kernel<<<dim3(4, 257), 256, 0, stream>>>(wsf + off_r, w_out, b_out, res);
        for (int s0 = 0; s0 < 64; s0 += nc) {
            int cur = (64 - s0 < nc) ? (64 - s0) : nc;
            fwd1_kernel<<<dim3(64, cur), 256, 0, stream>>>(x, Y, s0);
            midspec_kernel<<<dim3(33, cur), 512, 0, stream>>>(Y, res, s0);
            inv2_kernel<<<dim3(64, cur), 256, 0, stream>>>(Y, out, s0);
        }
    } else {
        rpe_mlp_kernel<<<4097, 64, 0, stream>>>(w_in, b_in, w_layers, b_layers,
                                                w_out, b_out, res);
        fftconv_kernel<<<4096, 256, 0, stream>>>(x, res, out);
    }
}